// Round 4
// baseline (780.624 us; speedup 1.0000x reference)
//
#include <hip/hip_runtime.h>

#define N_FINE   2000000
#define N_COARSE 500000
#define CCH      64

typedef float f32x4 __attribute__((ext_vector_type(4)));

// ---------- prep: quantize x (f32) -> int8 with per-row scale ----------
// 16 lanes per row; lane c4 owns channels [4*c4, 4*c4+4)
__global__ __launch_bounds__(256) void quant_i8_kernel(
    const float4* __restrict__ x4,   // [N_COARSE*16] float4
    char4*        __restrict__ xq4,  // [N_COARSE*16] char4
    float*        __restrict__ scales) // [N_COARSE]
{
    const int tid = blockIdx.x * blockDim.x + threadIdx.x;
    const int row = tid >> 4;
    const int c4  = tid & 15;
    if (row >= N_COARSE) return;

    float4 v = x4[tid];
    float amax = fmaxf(fmaxf(fabsf(v.x), fabsf(v.y)), fmaxf(fabsf(v.z), fabsf(v.w)));
#pragma unroll
    for (int m = 1; m < 16; m <<= 1)
        amax = fmaxf(amax, __shfl_xor(amax, m, 16));
    amax = fmaxf(amax, 1e-30f);

    const float inv = 127.0f / amax;
    char4 q;
    q.x = (signed char)(int)rintf(fminf(fmaxf(v.x * inv, -127.f), 127.f));
    q.y = (signed char)(int)rintf(fminf(fmaxf(v.y * inv, -127.f), 127.f));
    q.z = (signed char)(int)rintf(fminf(fmaxf(v.z * inv, -127.f), 127.f));
    q.w = (signed char)(int)rintf(fminf(fmaxf(v.w * inv, -127.f), 127.f));
    xq4[tid] = q;
    if (c4 == 0) scales[row] = amax * (1.0f / 127.0f);
}

// ---------- main: 16 lanes/face, each lane = 4 channels, int8 gathers ----------
__global__ __launch_bounds__(256) void smooth_upsample_i8(
    const char4* __restrict__ xq,       // [N_COARSE*16] char4 (64B per coarse row)
    const float* __restrict__ scales,   // [N_COARSE]
    const int*   __restrict__ nbr,      // [N_FINE, 9]
    const int*   __restrict__ pool_map, // [N_FINE]
    float*       __restrict__ out)      // [N_FINE, 64]
{
    const int tid = blockIdx.x * blockDim.x + threadIdx.x;
    const int f   = tid >> 4;
    const int c4  = tid & 15;
    if (f >= N_FINE) return;

    const float W[9] = {0.25f, 0.125f, 0.0625f, 0.125f, 0.0625f,
                        0.125f, 0.0625f, 0.125f, 0.0625f};

    const int* nrow = nbr + f * 9;

    float4 acc = make_float4(0.f, 0.f, 0.f, 0.f);
    float  corr = 0.f;

#pragma unroll
    for (int i = 0; i < 9; ++i) {
        int  nb    = __builtin_nontemporal_load(nrow + i);  // streamed: don't pollute L2
        bool valid = (nb != N_FINE);
        int  nbc   = valid ? nb : 0;
        int  pm    = pool_map[nbc];                         // reusable: cache normally
        char4 q    = xq[pm * 16 + c4];                      // 64B row, 1 transaction
        float s    = scales[pm];                            // 2MB, L2-resident
        float w    = valid ? W[i] : 0.f;
        float ws   = w * s;
        acc.x = fmaf(ws, (float)q.x, acc.x);
        acc.y = fmaf(ws, (float)q.y, acc.y);
        acc.z = fmaf(ws, (float)q.z, acc.z);
        acc.w = fmaf(ws, (float)q.w, acc.w);
        corr += w;
    }

    const float inv = 1.0f / corr;
    f32x4 o;
    o.x = acc.x * inv;
    o.y = acc.y * inv;
    o.z = acc.z * inv;
    o.w = acc.w * inv;
    __builtin_nontemporal_store(o, reinterpret_cast<f32x4*>(out) + tid);
}

// ---------- fallback (f32 gathers) if workspace too small ----------
__global__ __launch_bounds__(256) void smooth_upsample_f32(
    const float* __restrict__ x,
    const int*   __restrict__ nbr,
    const int*   __restrict__ pool_map,
    float*       __restrict__ out)
{
    const int tid = blockIdx.x * blockDim.x + threadIdx.x;
    const int f   = tid >> 4;
    const int c4  = tid & 15;
    if (f >= N_FINE) return;

    const float W[9] = {0.25f, 0.125f, 0.0625f, 0.125f, 0.0625f,
                        0.125f, 0.0625f, 0.125f, 0.0625f};
    const int* nrow = nbr + f * 9;
    float4 acc = make_float4(0.f, 0.f, 0.f, 0.f);
    float  corr = 0.f;
#pragma unroll
    for (int i = 0; i < 9; ++i) {
        int  nb    = nrow[i];
        bool valid = (nb != N_FINE);
        int  nbc   = valid ? nb : 0;
        int  pm    = pool_map[nbc];
        const float4* row = reinterpret_cast<const float4*>(x + (size_t)pm * CCH);
        float4 v = row[c4];
        float  w = valid ? W[i] : 0.f;
        acc.x = fmaf(w, v.x, acc.x);
        acc.y = fmaf(w, v.y, acc.y);
        acc.z = fmaf(w, v.z, acc.z);
        acc.w = fmaf(w, v.w, acc.w);
        corr += w;
    }
    const float inv = 1.0f / corr;
    f32x4 o;
    o.x = acc.x * inv;
    o.y = acc.y * inv;
    o.z = acc.z * inv;
    o.w = acc.w * inv;
    __builtin_nontemporal_store(o, reinterpret_cast<f32x4*>(out) + tid);
}

extern "C" void kernel_launch(void* const* d_in, const int* in_sizes, int n_in,
                              void* d_out, int out_size, void* d_ws, size_t ws_size,
                              hipStream_t stream) {
    const float* x        = (const float*)d_in[0];
    const int*   nbr      = (const int*)d_in[1];
    const int*   pool_map = (const int*)d_in[4];
    float*       out      = (float*)d_out;

    const size_t xq_bytes    = (size_t)N_COARSE * CCH;            // 32 MB int8
    const size_t scale_bytes = (size_t)N_COARSE * sizeof(float);  // 2 MB

    const long long total_threads = (long long)N_FINE * 16;
    const int block = 256;
    const int grid  = (int)((total_threads + block - 1) / block);  // 125000

    if (ws_size >= xq_bytes + scale_bytes) {
        char4* xq     = (char4*)d_ws;
        float* scales = (float*)((char*)d_ws + xq_bytes);
        const int prep_threads = N_COARSE * 16;  // 8M
        quant_i8_kernel<<<(prep_threads + 255) / 256, 256, 0, stream>>>(
            (const float4*)x, xq, scales);
        smooth_upsample_i8<<<grid, block, 0, stream>>>(xq, scales, nbr, pool_map, out);
    } else {
        smooth_upsample_f32<<<grid, block, 0, stream>>>(x, nbr, pool_map, out);
    }
}

// Round 5
// 614.294 us; speedup vs baseline: 1.2708x; 1.2708x over previous
//
#include <hip/hip_runtime.h>

#define N_FINE   2000000
#define N_COARSE 500000
#define CCH      64
#define PBITS    19
#define PMASK    ((1u << PBITS) - 1u)
// packed pool_map: 19 bits per entry
#define PWORDS   ((N_FINE * PBITS + 31) / 32)   // 1,187,500 words = 4.75 MB

typedef float f32x4 __attribute__((ext_vector_type(4)));
typedef unsigned long long u64;

// ---------- prep 1: convert x (f32) -> bf16 (round-to-nearest-even) ----------
__global__ __launch_bounds__(256) void conv_bf16_kernel(
    const float4* __restrict__ x4, ushort4* __restrict__ xb4, int n4)
{
    int i = blockIdx.x * blockDim.x + threadIdx.x;
    if (i >= n4) return;
    float4 v = x4[i];
    union { float f; unsigned u; } a;
    ushort4 o;
    a.f = v.x; o.x = (unsigned short)((a.u + 0x7FFFu + ((a.u >> 16) & 1u)) >> 16);
    a.f = v.y; o.y = (unsigned short)((a.u + 0x7FFFu + ((a.u >> 16) & 1u)) >> 16);
    a.f = v.z; o.z = (unsigned short)((a.u + 0x7FFFu + ((a.u >> 16) & 1u)) >> 16);
    a.f = v.w; o.w = (unsigned short)((a.u + 0x7FFFu + ((a.u >> 16) & 1u)) >> 16);
    xb4[i] = o;
}

// ---------- prep 2: pack pool_map (int32) -> 19-bit entries ----------
// one thread per OUTPUT word; word w covers global bits [32w, 32w+32)
__global__ __launch_bounds__(256) void pack_pool_kernel(
    const int* __restrict__ pool, unsigned* __restrict__ packed)
{
    int w = blockIdx.x * blockDim.x + threadIdx.x;
    if (w > PWORDS) return;          // one guard word at the end
    if (w == PWORDS) { packed[w] = 0u; return; }
    int i0 = (w * 32) / PBITS;       // first entry overlapping this word
    u64 acc = (u64)(unsigned)pool[i0];
    if (i0 + 1 < N_FINE) acc |= (u64)(unsigned)pool[i0 + 1] << PBITS;
    if (i0 + 2 < N_FINE) acc |= (u64)(unsigned)pool[i0 + 2] << (2 * PBITS);
    int sh = 32 * w - PBITS * i0;    // in [0, 18]
    packed[w] = (unsigned)(acc >> sh);
}

__device__ __forceinline__ int unpack_pool(const unsigned* __restrict__ pp, int idx)
{
    int bo = idx * PBITS;
    int w  = bo >> 5;
    int s  = bo & 31;
    u64 v  = ((u64)pp[w + 1] << 32) | pp[w];
    return (int)((v >> s) & PMASK);
}

// ---------- main: 16 lanes/face, each lane = 4 channels, bf16 gathers ----------
__global__ __launch_bounds__(256) void smooth_upsample_bf16(
    const ushort*   __restrict__ xb,   // [N_COARSE, 64] bf16
    const unsigned* __restrict__ pp,   // packed pool_map, 19b/entry (4.75 MB, L2-resident)
    const int*      __restrict__ nbr,  // [N_FINE, 9]
    float*          __restrict__ out)  // [N_FINE, 64]
{
    const int tid = blockIdx.x * blockDim.x + threadIdx.x;
    const int f   = tid >> 4;
    const int c4  = tid & 15;
    if (f >= N_FINE) return;

    const float W[9] = {0.25f, 0.125f, 0.0625f, 0.125f, 0.0625f,
                        0.125f, 0.0625f, 0.125f, 0.0625f};

    const int* nrow = nbr + f * 9;

    float4 acc = make_float4(0.f, 0.f, 0.f, 0.f);
    float  corr = 0.25f;   // tap 0 always valid (nbr[f][0] == f)

    // tap 0: nb == f, sequential pool access, always valid
    {
        int pm = unpack_pool(pp, f);
        const ushort4* row = reinterpret_cast<const ushort4*>(xb + (size_t)pm * CCH);
        ushort4 v = row[c4];
        acc.x = 0.25f * __uint_as_float((unsigned)v.x << 16);
        acc.y = 0.25f * __uint_as_float((unsigned)v.y << 16);
        acc.z = 0.25f * __uint_as_float((unsigned)v.z << 16);
        acc.w = 0.25f * __uint_as_float((unsigned)v.w << 16);
    }

#pragma unroll
    for (int i = 1; i < 9; ++i) {
        int  nb    = nrow[i];
        bool valid = (nb != N_FINE);
        int  nbc   = valid ? nb : 0;
        int  pm    = unpack_pool(pp, nbc);
        ushort4 v  = *reinterpret_cast<const ushort4*>(xb + (size_t)pm * CCH + c4 * 4);
        float w    = valid ? W[i] : 0.f;
        acc.x = fmaf(w, __uint_as_float((unsigned)v.x << 16), acc.x);
        acc.y = fmaf(w, __uint_as_float((unsigned)v.y << 16), acc.y);
        acc.z = fmaf(w, __uint_as_float((unsigned)v.z << 16), acc.z);
        acc.w = fmaf(w, __uint_as_float((unsigned)v.w << 16), acc.w);
        corr += w;
    }

    const float inv = 1.0f / corr;
    f32x4 o;
    o.x = acc.x * inv;
    o.y = acc.y * inv;
    o.z = acc.z * inv;
    o.w = acc.w * inv;
    __builtin_nontemporal_store(o, reinterpret_cast<f32x4*>(out) + tid);
}

// ---------- fallback (f32 gathers) if workspace too small ----------
__global__ __launch_bounds__(256) void smooth_upsample_f32(
    const float* __restrict__ x,
    const int*   __restrict__ nbr,
    const int*   __restrict__ pool_map,
    float*       __restrict__ out)
{
    const int tid = blockIdx.x * blockDim.x + threadIdx.x;
    const int f   = tid >> 4;
    const int c4  = tid & 15;
    if (f >= N_FINE) return;

    const float W[9] = {0.25f, 0.125f, 0.0625f, 0.125f, 0.0625f,
                        0.125f, 0.0625f, 0.125f, 0.0625f};
    const int* nrow = nbr + f * 9;
    float4 acc = make_float4(0.f, 0.f, 0.f, 0.f);
    float  corr = 0.f;
#pragma unroll
    for (int i = 0; i < 9; ++i) {
        int  nb    = nrow[i];
        bool valid = (nb != N_FINE);
        int  nbc   = valid ? nb : 0;
        int  pm    = pool_map[nbc];
        const float4* row = reinterpret_cast<const float4*>(x + (size_t)pm * CCH);
        float4 v = row[c4];
        float  w = valid ? W[i] : 0.f;
        acc.x = fmaf(w, v.x, acc.x);
        acc.y = fmaf(w, v.y, acc.y);
        acc.z = fmaf(w, v.z, acc.z);
        acc.w = fmaf(w, v.w, acc.w);
        corr += w;
    }
    const float inv = 1.0f / corr;
    f32x4 o;
    o.x = acc.x * inv;
    o.y = acc.y * inv;
    o.z = acc.z * inv;
    o.w = acc.w * inv;
    __builtin_nontemporal_store(o, reinterpret_cast<f32x4*>(out) + tid);
}

extern "C" void kernel_launch(void* const* d_in, const int* in_sizes, int n_in,
                              void* d_out, int out_size, void* d_ws, size_t ws_size,
                              hipStream_t stream) {
    const float* x        = (const float*)d_in[0];
    const int*   nbr      = (const int*)d_in[1];
    const int*   pool_map = (const int*)d_in[4];
    float*       out      = (float*)d_out;

    const size_t xb_bytes = (size_t)N_COARSE * CCH * sizeof(unsigned short); // 64 MB
    const size_t pp_bytes = (size_t)(PWORDS + 1) * sizeof(unsigned);         // ~4.75 MB

    const long long total_threads = (long long)N_FINE * 16;
    const int block = 256;
    const int grid  = (int)((total_threads + block - 1) / block);  // 125000

    if (ws_size >= xb_bytes + pp_bytes) {
        ushort*   xb = (ushort*)d_ws;
        unsigned* pp = (unsigned*)((char*)d_ws + xb_bytes);

        const int n4 = N_COARSE * CCH / 4;  // 8M float4 groups
        conv_bf16_kernel<<<(n4 + 255) / 256, 256, 0, stream>>>(
            (const float4*)x, (ushort4*)xb, n4);
        pack_pool_kernel<<<(PWORDS + 1 + 255) / 256, 256, 0, stream>>>(pool_map, pp);

        smooth_upsample_bf16<<<grid, block, 0, stream>>>(xb, pp, nbr, out);
    } else {
        smooth_upsample_f32<<<grid, block, 0, stream>>>(x, nbr, pool_map, out);
    }
}